// Round 1
// baseline (609.513 us; speedup 1.0000x reference)
//
#include <hip/hip_runtime.h>
#include <hip/hip_bf16.h>

#define N_NODES 50000
#define N_EDGES 800000
#define NODE_DIM 256
#define EDGE_DIM 64
#define HIDDEN 512
#define OUT_DIM 256
#define IN_DIM 320   // EDGE_DIM + NODE_DIM

typedef __bf16 bf16_t;
typedef bf16_t bf16x8 __attribute__((ext_vector_type(8)));
typedef float floatx4 __attribute__((ext_vector_type(4)));

__device__ inline bf16_t to_bf16(float f) {
    __hip_bfloat16 h = __float2bfloat16(f);
    bf16_t b;
    __builtin_memcpy(&b, &h, 2);
    return b;
}

// ---------------------------------------------------------------------------
// Kernel 1: scatter edge features to target nodes (atomic). 1 wave per edge,
// lane d handles dim d. Coalesced 4B reads of edge_features; idx read is a
// 64-lane broadcast (same address).
// ---------------------------------------------------------------------------
__global__ __launch_bounds__(256) void scatter_edges(
    const float* __restrict__ ef, const int* __restrict__ eidx,
    float* __restrict__ agg, float* __restrict__ counts) {
    int gid = blockIdx.x * 256 + threadIdx.x;
    int e = gid >> 6;
    int d = gid & 63;
    if (e >= N_EDGES) return;
    int t = eidx[N_EDGES + e];          // row 1 = target
    t = min(max(t, 0), N_NODES - 1);    // defensive clamp
    float v = ef[(size_t)e * EDGE_DIM + d];
    atomicAdd(&agg[(size_t)t * EDGE_DIM + d], v);
    if (d == 0) atomicAdd(&counts[t], 1.0f);
}

// ---------------------------------------------------------------------------
// Kernel 2: combined = concat(agg/max(cnt,1), node_features) cast to bf16
// ---------------------------------------------------------------------------
__global__ __launch_bounds__(256) void build_combined(
    const float* __restrict__ agg, const float* __restrict__ counts,
    const float* __restrict__ node, bf16_t* __restrict__ combined) {
    int idx = blockIdx.x * 256 + threadIdx.x;
    if (idx >= N_NODES * IN_DIM) return;
    int i = idx / IN_DIM;
    int d = idx - i * IN_DIM;
    float v;
    if (d < EDGE_DIM) {
        float c = counts[i];
        v = agg[(size_t)i * EDGE_DIM + d] / fmaxf(c, 1.0f);
    } else {
        v = node[(size_t)i * NODE_DIM + (d - EDGE_DIM)];
    }
    combined[idx] = to_bf16(v);
}

// ---------------------------------------------------------------------------
// Kernel 3: W1 [320,512] -> W1T bf16 [512,320]; W2 [512,256] -> W2T bf16 [256,512]
// (transposed so GEMM reads B as BT[n][k], 8 contiguous k per fragment)
// ---------------------------------------------------------------------------
__global__ __launch_bounds__(256) void convert_weights(
    const float* __restrict__ W1, const float* __restrict__ W2,
    bf16_t* __restrict__ W1T, bf16_t* __restrict__ W2T) {
    int idx = blockIdx.x * 256 + threadIdx.x;
    if (idx < IN_DIM * HIDDEN) {
        int k = idx / HIDDEN, n = idx - k * HIDDEN;
        W1T[(size_t)n * IN_DIM + k] = to_bf16(W1[idx]);
    } else {
        int j = idx - IN_DIM * HIDDEN;
        if (j < HIDDEN * OUT_DIM) {
            int k = j / OUT_DIM, n = j - k * OUT_DIM;
            W2T[(size_t)n * HIDDEN + k] = to_bf16(W2[j]);
        }
    }
}

// ---------------------------------------------------------------------------
// Kernel 4/5: C[M,N] = act(A[M,K] @ BT[N,K]^T + bias)
// 128x128 block tile, BK=32, 4 waves in 2x2, each wave 4x4 16x16x32 MFMAs.
// Verified gfx950 layouts: A-frag m=lane&15,k=quad*8+j; B-frag n=lane&15;
// C/D col=lane&15, row=quad*4+reg.
// ---------------------------------------------------------------------------
template <bool RELU, bool OUT_BF16>
__global__ __launch_bounds__(256) void gemm_bt(
    const bf16_t* __restrict__ A, const bf16_t* __restrict__ BT,
    const float* __restrict__ bias, void* __restrict__ Cout,
    int M, int N, int K) {
    __shared__ bf16_t As[128][40];  // +8 pad: 80B row stride, 16B aligned
    __shared__ bf16_t Bs[128][40];

    const int tid = threadIdx.x;
    const int lane = tid & 63;
    const int w = tid >> 6;
    const int wm = (w & 1) * 64;
    const int wn = (w >> 1) * 64;
    const int lrow = lane & 15;
    const int quad = lane >> 4;
    const int kq = quad * 8;
    const int m0 = blockIdx.x * 128;
    const int n0 = blockIdx.y * 128;

    floatx4 acc[4][4] = {};

    const int nkt = K / 32;
    for (int kt = 0; kt < nkt; ++kt) {
        const int k0 = kt * 32;
        __syncthreads();
#pragma unroll
        for (int it = 0; it < 2; ++it) {
            int slot = tid + it * 256;
            int row = slot >> 2;
            int cg = (slot & 3) * 8;
            int gm = m0 + row;
            uint4 va = {0u, 0u, 0u, 0u};
            if (gm < M)
                va = *reinterpret_cast<const uint4*>(&A[(size_t)gm * K + k0 + cg]);
            *reinterpret_cast<uint4*>(&As[row][cg]) = va;
            int gn = n0 + row;  // N is a multiple of 128 -> always in range
            uint4 vb = *reinterpret_cast<const uint4*>(&BT[(size_t)gn * K + k0 + cg]);
            *reinterpret_cast<uint4*>(&Bs[row][cg]) = vb;
        }
        __syncthreads();

        bf16x8 af[4], bfr[4];
#pragma unroll
        for (int mi = 0; mi < 4; ++mi)
            af[mi] = *reinterpret_cast<const bf16x8*>(&As[wm + mi * 16 + lrow][kq]);
#pragma unroll
        for (int ni = 0; ni < 4; ++ni)
            bfr[ni] = *reinterpret_cast<const bf16x8*>(&Bs[wn + ni * 16 + lrow][kq]);
#pragma unroll
        for (int mi = 0; mi < 4; ++mi)
#pragma unroll
            for (int ni = 0; ni < 4; ++ni)
                acc[mi][ni] = __builtin_amdgcn_mfma_f32_16x16x32_bf16(
                    af[mi], bfr[ni], acc[mi][ni], 0, 0, 0);
    }

    // Epilogue
#pragma unroll
    for (int ni = 0; ni < 4; ++ni) {
        int gn = n0 + wn + ni * 16 + lrow;
        float bv = bias[gn];
#pragma unroll
        for (int mi = 0; mi < 4; ++mi) {
            int gmb = m0 + wm + mi * 16 + quad * 4;
#pragma unroll
            for (int r = 0; r < 4; ++r) {
                int gm = gmb + r;
                if (gm < M) {
                    float v = acc[mi][ni][r] + bv;
                    if (RELU) v = fmaxf(v, 0.0f);
                    if (OUT_BF16)
                        ((bf16_t*)Cout)[(size_t)gm * N + gn] = to_bf16(v);
                    else
                        ((float*)Cout)[(size_t)gm * N + gn] = v;
                }
            }
        }
    }
}

// ---------------------------------------------------------------------------
extern "C" void kernel_launch(void* const* d_in, const int* in_sizes, int n_in,
                              void* d_out, int out_size, void* d_ws, size_t ws_size,
                              hipStream_t stream) {
    const float* node = (const float*)d_in[0];
    const int* eidx = (const int*)d_in[1];
    const float* ef = (const float*)d_in[2];
    const float* W1 = (const float*)d_in[3];
    const float* b1 = (const float*)d_in[4];
    const float* W2 = (const float*)d_in[5];
    const float* b2 = (const float*)d_in[6];
    float* out = (float*)d_out;

    char* ws = (char*)d_ws;
    float* agg = (float*)ws;                              // 12,800,000 B
    float* counts = (float*)(ws + 12800000);              //    200,000 B
    bf16_t* combined = (bf16_t*)(ws + 13000000);          // 32,000,000 B
    bf16_t* h = (bf16_t*)(ws + 45000000);                 // 51,200,000 B
    bf16_t* W1T = (bf16_t*)(ws + 96200000);               //    327,680 B
    bf16_t* W2T = (bf16_t*)(ws + 96527680);               //    262,144 B

    // zero agg + counts (ws is poisoned 0xAA before every launch)
    hipMemsetAsync(ws, 0, 13000000, stream);

    scatter_edges<<<(N_EDGES * 64) / 256, 256, 0, stream>>>(ef, eidx, agg, counts);

    build_combined<<<(N_NODES * IN_DIM + 255) / 256, 256, 0, stream>>>(
        agg, counts, node, combined);

    convert_weights<<<(IN_DIM * HIDDEN + HIDDEN * OUT_DIM + 255) / 256, 256, 0, stream>>>(
        W1, W2, W1T, W2T);

    // h = relu(combined @ W1 + b1)   [50000,512] bf16
    gemm_bt<true, true><<<dim3((N_NODES + 127) / 128, HIDDEN / 128), 256, 0, stream>>>(
        combined, W1T, b1, (void*)h, N_NODES, HIDDEN, IN_DIM);

    // out = h @ W2 + b2              [50000,256] f32
    gemm_bt<false, false><<<dim3((N_NODES + 127) / 128, OUT_DIM / 128), 256, 0, stream>>>(
        h, W2T, b2, (void*)out, N_NODES, OUT_DIM, HIDDEN);
}